// Round 4
// baseline (916.804 us; speedup 1.0000x reference)
//
#include <hip/hip_runtime.h>
#include <hip/hip_fp16.h>

typedef __half f16;
typedef _Float16 h8 __attribute__((ext_vector_type(8)));
typedef _Float16 h4 __attribute__((ext_vector_type(4)));
typedef float f32x4 __attribute__((ext_vector_type(4)));

#define NN 255          // real nodes
#define BB 512          // batch
#define M2 131072       // 512 * 256 node-padded rows
#define TS 260          // T LDS row stride in f16 (520 B: 8B-aligned, 4-way banks on b64)

static __device__ __forceinline__ float h2f(f16 x) { return __half2float(x); }
static __device__ __forceinline__ f16 f2h(float x) { return __float2half(x); }

// ---------------- DAD build (tiny) ----------------

__global__ void zero_k(float* p, int n) {
    int i = blockIdx.x * 256 + threadIdx.x;
    if (i < n) p[i] = 0.f;
}

__global__ void scatter_k(const int* __restrict__ idx, const float* __restrict__ vals,
                          float* __restrict__ dad, int nnz) {
    int t = blockIdx.x * 256 + threadIdx.x;
    if (t < nnz) atomicAdd(&dad[idx[2 * t] * 256 + idx[2 * t + 1]], vals[t]);
}

__global__ void rowsum_k(const float* __restrict__ dad, float* __restrict__ r) {
    int i = blockIdx.x * 64 + threadIdx.x;
    if (i < NN) {
        float s = 0.f;
        for (int k = 0; k < NN; k++) s += dad[i * 256 + k];
        r[i] = s;
    }
}

// dadh[256][256] f16 from dadf[255][256] f32; row 255 = 0
__global__ void convert_dad(const float* __restrict__ dadf, f16* __restrict__ dadh) {
    int i = blockIdx.x * 256 + threadIdx.x;   // over 2*65536
    int which = i >> 16, rc = i & 65535;
    int row = rc >> 8;
    float v = (row < NN) ? dadf[(size_t)which * NN * 256 + rc] : 0.f;
    dadh[(size_t)which * 65536 + rc] = f2h(v);
}

// Wt[n][k] = W[k][n], zero-padded to [gridDim.x rows][Kpad]
__global__ void convert_wt(const float* __restrict__ W, f16* __restrict__ Wt,
                           int K, int N, int Kpad) {
    int n = blockIdx.x;
    for (int k = threadIdx.x; k < Kpad; k += 256) {
        float v = (n < N && k < K) ? W[(size_t)k * N + n] : 0.f;
        Wt[(size_t)n * Kpad + k] = f2h(v);
    }
}

// ============ fused layer: Xn[b][node][n0+f] = relu( DAD @ (X[b]@W + bias) ) ============
// Stage 1 (barrier-free): T[feat][node] = (X[b] @ W_tile)^T + bias
//   A-op = X rows (node), B-op = Wt rows (feat); frags straight from global (L1/L2-hot).
// Stage 2 (barrier-free): D[feat][node_out] = sum_k T[feat][k] * dadh[node_out][k]
//   A-op = T from LDS, B-op = dadh from global (128 KB, L1-hot); 8-B packed stores.
template <int KP>
__global__ __launch_bounds__(256, 2) void fused_layer(
        const f16* __restrict__ X,      // [512][256][KP], k-pads zero
        const f16* __restrict__ Wt,     // [ntiles*128][KP], zero-padded
        const float* __restrict__ bias, // [Nout] f32
        const f16* __restrict__ dadh,   // [256][256], row 255 zero
        f16* __restrict__ Xn,           // [512][256][SN]
        int Nout, int SN) {
    __shared__ _Float16 T[128 * TS];
    const int b = blockIdx.x;
    const int n0 = blockIdx.y * 128;
    const int tid = threadIdx.x;
    const int w = tid >> 6;
    const int ln = tid & 15, q = (tid & 63) >> 4;

    // ---- stage 1: wave w covers nodes 64w..64w+63 (4 row-tiles) x 128 feats (8 col-tiles)
    f32x4 acc[4][8];
#pragma unroll
    for (int t = 0; t < 4; t++)
#pragma unroll
        for (int c = 0; c < 8; c++) acc[t][c] = (f32x4){0.f, 0.f, 0.f, 0.f};

    const f16* xA = X + (size_t)b * 256 * KP;
    for (int k = 0; k < KP; k += 32) {
        h8 af[4], bf[8];
#pragma unroll
        for (int t = 0; t < 4; t++)
            af[t] = *(const h8*)(xA + (size_t)(64 * w + 16 * t + ln) * KP + k + q * 8);
#pragma unroll
        for (int c = 0; c < 8; c++)
            bf[c] = *(const h8*)(Wt + (size_t)(n0 + 16 * c + ln) * KP + k + q * 8);
#pragma unroll
        for (int t = 0; t < 4; t++)
#pragma unroll
            for (int c = 0; c < 8; c++)
                acc[t][c] = __builtin_amdgcn_mfma_f32_16x16x32_f16(af[t], bf[c], acc[t][c], 0, 0, 0);
    }

    // bias + pack to T[feat][node] (lane holds 4 consecutive nodes -> b64 writes)
#pragma unroll
    for (int c = 0; c < 8; c++) {
        int fl = 16 * c + ln;
        int bi = n0 + fl;
        float bv = bias[bi < Nout ? bi : 0];
#pragma unroll
        for (int t = 0; t < 4; t++) {
            h4 pk;
#pragma unroll
            for (int rg = 0; rg < 4; rg++) pk[rg] = (_Float16)(acc[t][c][rg] + bv);
            *(h4*)&T[fl * TS + 64 * w + 16 * t + q * 4] = pk;
        }
    }
    __syncthreads();

    // ---- stage 2: wave w covers feats 32w..32w+31 (2 row-tiles) x 256 node_out (16 col-tiles)
    f32x4 acc2[2][16];
#pragma unroll
    for (int t = 0; t < 2; t++)
#pragma unroll
        for (int c = 0; c < 16; c++) acc2[t][c] = (f32x4){0.f, 0.f, 0.f, 0.f};

    for (int k = 0; k < 256; k += 32) {
        h8 a2[2];
#pragma unroll
        for (int t = 0; t < 2; t++) {
            const _Float16* tp = &T[(32 * w + 16 * t + ln) * TS + k + q * 8];
            union { h8 v; h4 h[2]; } u;
            u.h[0] = *(const h4*)tp;
            u.h[1] = *(const h4*)(tp + 4);
            a2[t] = u.v;
        }
#pragma unroll
        for (int half = 0; half < 2; half++) {
            h8 b2[8];
#pragma unroll
            for (int c = 0; c < 8; c++)
                b2[c] = *(const h8*)(dadh + (size_t)(16 * (8 * half + c) + ln) * 256 + k + q * 8);
#pragma unroll
            for (int t = 0; t < 2; t++)
#pragma unroll
                for (int c = 0; c < 8; c++)
                    acc2[t][8 * half + c] =
                        __builtin_amdgcn_mfma_f32_16x16x32_f16(a2[t], b2[c], acc2[t][8 * half + c], 0, 0, 0);
        }
    }

    // epilogue: relu, pack 4 consecutive feats, 8-B stores; zero-fill pad feats
    f16* xnb = Xn + (size_t)b * 256 * SN;
#pragma unroll
    for (int t = 0; t < 2; t++) {
        int fb = n0 + 32 * w + 16 * t + q * 4;   // global feat group base (mult of 4)
        if (fb >= SN) continue;
        bool real = fb < Nout;                   // Nout mult of 4: groups never straddle
#pragma unroll
        for (int c = 0; c < 16; c++) {
            int node = 16 * c + ln;
            h4 pk;
#pragma unroll
            for (int rg = 0; rg < 4; rg++)
                pk[rg] = real ? (_Float16)fmaxf(acc2[t][c][rg], 0.f) : (_Float16)0.f;
            *(h4*)(xnb + (size_t)node * SN + fb) = pk;
        }
    }
}

// ---------------- L0: T0[b][256][2] = DADsm @ H (f32 in, f16 out, no relu) ----------------
__global__ __launch_bounds__(256) void dad2_in(const float* __restrict__ dad,
                                               const float* __restrict__ H,
                                               f16* __restrict__ T0) {
    int gw = (blockIdx.x * 256 + threadIdx.x) >> 6;
    int lane = threadIdx.x & 63;
    if (gw >= BB * NN) return;
    int b = gw / NN, i = gw - b * NN;
    const float* dr = dad + (size_t)i * 256;
    const float* yb = H + (size_t)b * NN * 2;
    float a0 = 0.f, a1 = 0.f;
    for (int k = lane; k < NN; k += 64) {
        float d = dr[k];
        a0 += d * yb[2 * k];
        a1 += d * yb[2 * k + 1];
    }
#pragma unroll
    for (int off = 32; off > 0; off >>= 1) {
        a0 += __shfl_down(a0, off);
        a1 += __shfl_down(a1, off);
    }
    if (lane == 0) {
        T0[((size_t)b * 256 + i) * 2 + 0] = f2h(a0);
        T0[((size_t)b * 256 + i) * 2 + 1] = f2h(a1);
    }
}

// ---------------- L0 expand: X0[m][416] = relu(T0 @ W0 + r[node]*b0), pads zero ----------------
__global__ __launch_bounds__(256) void expand2_k(const f16* __restrict__ T0,
                                                 const float* __restrict__ W0,
                                                 const float* __restrict__ b0,
                                                 const float* __restrict__ rsm,
                                                 f16* __restrict__ X0) {
    int m = blockIdx.x;          // over M2
    int node = m & 255;
    bool pad = (node == NN);
    float a0 = 0.f, a1 = 0.f, rv = 0.f;
    if (!pad) {
        a0 = h2f(T0[(size_t)m * 2]);
        a1 = h2f(T0[(size_t)m * 2 + 1]);
        rv = rsm[node];
    }
    for (int n = threadIdx.x; n < 416; n += 256) {
        float v = 0.f;
        if (!pad && n < 400) v = fmaxf(a0 * W0[n] + a1 * W0[400 + n] + rv * b0[n], 0.f);
        X0[(size_t)m * 416 + n] = f2h(v);
    }
}

// ---------------- L5: T5[m][2] = X4 @ W5 + b5 (X4 stride 416) ----------------
__global__ __launch_bounds__(256) void dense2(const f16* __restrict__ X4,
                                              const float* __restrict__ W5,
                                              const float* __restrict__ b5,
                                              f16* __restrict__ T5) {
    int gw = (blockIdx.x * 256 + threadIdx.x) >> 6;
    int lane = threadIdx.x & 63;
    if (gw >= M2) return;
    const f16* xr = X4 + (size_t)gw * 416;
    float a0 = 0.f, a1 = 0.f;
    for (int k = lane; k < 400; k += 64) {
        float x = h2f(xr[k]);
        a0 += x * W5[2 * k];
        a1 += x * W5[2 * k + 1];
    }
#pragma unroll
    for (int off = 32; off > 0; off >>= 1) {
        a0 += __shfl_down(a0, off);
        a1 += __shfl_down(a1, off);
    }
    if (lane == 0) {
        T5[(size_t)gw * 2 + 0] = f2h(a0 + b5[0]);
        T5[(size_t)gw * 2 + 1] = f2h(a1 + b5[1]);
    }
}

// ---------------- final: out[b][i][2] = relu(DADsp @ T5) (f32 out, unpadded) ----------------
__global__ __launch_bounds__(256) void dad2_out(const float* __restrict__ dad,
                                                const f16* __restrict__ T5,
                                                float* __restrict__ out) {
    int gw = (blockIdx.x * 256 + threadIdx.x) >> 6;
    int lane = threadIdx.x & 63;
    if (gw >= BB * NN) return;
    int b = gw / NN, i = gw - b * NN;
    const float* dr = dad + (size_t)i * 256;
    const f16* yb = T5 + (size_t)b * 512;
    float a0 = 0.f, a1 = 0.f;
    for (int k = lane; k < NN; k += 64) {
        float d = dr[k];
        a0 += d * h2f(yb[2 * k]);
        a1 += d * h2f(yb[2 * k + 1]);
    }
#pragma unroll
    for (int off = 32; off > 0; off >>= 1) {
        a0 += __shfl_down(a0, off);
        a1 += __shfl_down(a1, off);
    }
    if (lane == 0) {
        out[((size_t)b * NN + i) * 2 + 0] = fmaxf(a0, 0.f);
        out[((size_t)b * NN + i) * 2 + 1] = fmaxf(a1, 0.f);
    }
}

// ---------------- launcher ----------------

extern "C" void kernel_launch(void* const* d_in, const int* in_sizes, int n_in,
                              void* d_out, int out_size, void* d_ws, size_t ws_size,
                              hipStream_t stream) {
    const float* H   = (const float*)d_in[0];
    const float* W[6]  = {(const float*)d_in[3], (const float*)d_in[5], (const float*)d_in[7],
                          (const float*)d_in[9], (const float*)d_in[11], (const float*)d_in[13]};
    const float* Bv[6] = {(const float*)d_in[4], (const float*)d_in[6], (const float*)d_in[8],
                          (const float*)d_in[10], (const float*)d_in[12], (const float*)d_in[14]};
    const int* smi = (const int*)d_in[15];
    const int* spi = (const int*)d_in[16];
    float* out = (float*)d_out;

    char* p = (char*)d_ws;
    f16* bufA = (f16*)p;            p += 109051904;   // X0/X2/X4 (max stride 416)
    f16* bufB = (f16*)p;            p += 83886080;    // X1/X3 (max stride 320)
    float* dadsm = (float*)p;       p += 261120;      // [255][256] f32
    float* dadsp = (float*)p;       p += 261120;
    float* rsm = (float*)p;         p += 1024;
    f16* dadhsm = (f16*)p;          p += 131072;      // [256][256] f16
    f16* dadhsp = (f16*)p;          p += 131072;
    f16* Wt1 = (f16*)p;             p += 319488;      // [384][416]
    f16* Wt2 = (f16*)p;             p += 81920;       // [128][320]
    f16* Wt3 = (f16*)p;             p += 98304;       // [384][128]
    f16* Wt4 = (f16*)p;             p += 327680;      // [512][320]
    f16* T0 = (f16*)p;              p += 524288;      // [131072][2]
    f16* T5 = (f16*)p;              p += 524288;

    // ---- build DAD + weight conversion ----
    zero_k<<<510, 256, 0, stream>>>(dadsm, 2 * NN * 256);
    scatter_k<<<10, 256, 0, stream>>>(smi, (const float*)d_in[1], dadsm, 2550);
    scatter_k<<<10, 256, 0, stream>>>(spi, (const float*)d_in[2], dadsp, 2550);
    rowsum_k<<<4, 64, 0, stream>>>(dadsm, rsm);
    convert_dad<<<512, 256, 0, stream>>>(dadsm, dadhsm);
    convert_wt<<<384, 256, 0, stream>>>(W[1], Wt1, 400, 300, 416);
    convert_wt<<<128, 256, 0, stream>>>(W[2], Wt2, 300, 100, 320);
    convert_wt<<<384, 256, 0, stream>>>(W[3], Wt3, 100, 300, 128);
    convert_wt<<<512, 256, 0, stream>>>(W[4], Wt4, 300, 400, 320);

    const int nwb = (BB * NN * 64 + 255) / 256;   // 32640
    const int nwb2 = (M2 * 64) / 256;             // 32768

    // L0 enc0 (2->400), DAD-first via row-sum trick: X0 = relu((DADsm H) W0 + r b0)
    dad2_in<<<nwb, 256, 0, stream>>>(dadsm, H, T0);
    expand2_k<<<M2, 256, 0, stream>>>(T0, W[0], Bv[0], rsm, bufA);

    // L1 enc1 (400->300): X1 = relu(DADsm @ (X0 W1 + b1))
    fused_layer<416><<<dim3(BB, 3), 256, 0, stream>>>(bufA, Wt1, Bv[1], dadhsm, bufB, 300, 320);
    // L2 enc2 (300->100): X2 = relu(DADsm @ (X1 W2 + b2))
    fused_layer<320><<<dim3(BB, 1), 256, 0, stream>>>(bufB, Wt2, Bv[2], dadhsm, bufA, 100, 128);
    // L3 dec0 (100->300): X3 = relu(DADsp @ (X2 W3 + b3))
    fused_layer<128><<<dim3(BB, 3), 256, 0, stream>>>(bufA, Wt3, Bv[3], dadhsp, bufB, 300, 320);
    // L4 dec1 (300->400): X4 = relu(DADsp @ (X3 W4 + b4))
    fused_layer<320><<<dim3(BB, 4), 256, 0, stream>>>(bufB, Wt4, Bv[4], dadhsp, bufA, 400, 416);

    // L5 dec2 (400->2): T5 = X4@W5 + b5 ; out = relu(DADsp @ T5)
    dense2<<<nwb2, 256, 0, stream>>>(bufA, W[5], Bv[5], T5);
    dad2_out<<<nwb, 256, 0, stream>>>(dadsp, T5, out);
}

// Round 5
// 702.009 us; speedup vs baseline: 1.3060x; 1.3060x over previous
//
#include <hip/hip_runtime.h>
#include <hip/hip_fp16.h>

typedef __half f16;
typedef _Float16 h8 __attribute__((ext_vector_type(8)));
typedef _Float16 h4 __attribute__((ext_vector_type(4)));
typedef float f32x4 __attribute__((ext_vector_type(4)));

#define NN 255          // real nodes
#define BB 512          // batch
#define TSS 264         // T LDS row stride in f16 (528 B; stride%32words==4 -> conflict-free b128/b64)

static __device__ __forceinline__ f16 f2h(float x) { return __float2half(x); }

// ---------------- setup kernels (tiny) ----------------

__global__ void zero_k(float* p, int n) {
    int i = blockIdx.x * 256 + threadIdx.x;
    if (i < n) p[i] = 0.f;
}

__global__ void scatter_k(const int* __restrict__ idx, const float* __restrict__ vals,
                          float* __restrict__ dad, int nnz) {
    int t = blockIdx.x * 256 + threadIdx.x;
    if (t < nnz) atomicAdd(&dad[idx[2 * t] * 256 + idx[2 * t + 1]], vals[t]);
}

// dadh[256][256] f16 from dadf[255][256] f32; row 255 = 0 (col 255 never written by scatter)
__global__ void convert_dad(const float* __restrict__ dadf, f16* __restrict__ dadh) {
    int i = blockIdx.x * 256 + threadIdx.x;   // over 2*65536
    int which = i >> 16, rc = i & 65535;
    int row = rc >> 8;
    float v = (row < NN) ? dadf[(size_t)which * NN * 256 + rc] : 0.f;
    dadh[(size_t)which * 65536 + rc] = f2h(v);
}

// Wt[n][k] = W[k][n], zero-padded to [gridDim.x rows][Kpad]
__global__ void convert_wt(const float* __restrict__ W, f16* __restrict__ Wt,
                           int K, int N, int Kpad) {
    int n = blockIdx.x;
    for (int k = threadIdx.x; k < Kpad; k += 256) {
        float v = (n < N && k < K) ? W[(size_t)k * N + n] : 0.f;
        Wt[(size_t)n * Kpad + k] = f2h(v);
    }
}

// Hp[b][node][32] f16: k 0,1 = H[b][node][0..1], rest 0; node 255 row = 0
__global__ __launch_bounds__(256) void pack_h(const float* __restrict__ H, f16* __restrict__ Hp) {
    int g = blockIdx.x * 256 + threadIdx.x;   // over 131072
    int b = g >> 8, node = g & 255;
    _Float16 v0 = (_Float16)0.f, v1 = (_Float16)0.f;
    if (node < NN) {
        v0 = (_Float16)H[((size_t)b * NN + node) * 2];
        v1 = (_Float16)H[((size_t)b * NN + node) * 2 + 1];
    }
    h8 z;
#pragma unroll
    for (int i = 0; i < 8; i++) z[i] = (_Float16)0.f;
    h8 h0 = z; h0[0] = v0; h0[1] = v1;
    _Float16* dst = (_Float16*)Hp + (size_t)g * 32;
    *(h8*)dst = h0;
    *(h8*)(dst + 8) = z;
    *(h8*)(dst + 16) = z;
    *(h8*)(dst + 24) = z;
}

// ============ fused layer: Xn = relu( DAD @ (X@W + bias) ), one (b, 64-feat tile) per block ============
// Stage 1 (barrier-free): T[64 feat][256 node] = (X[b] @ W_tile)^T + bias. Frags from global.
//   wave w: nodes 64w..64w+63 (A-op, 4 tiles) x 64 feats (B-op, 4 tiles), acc 4x4 f32x4.
// Stage 2 (barrier-free): out[feat][node_out] = sum_k T[feat][k] * dadh[node_out][k].
//   wave w: all 64 feats (A-op from LDS T) x node_outs 64w..64w+63 (B-op dadh, L2-hot), acc 4x4.
// One __syncthreads total. Pad feats: Wt rows & bias are 0 -> T=0 -> output 0. Pad node 255:
// X row 0 -> T=bias, but dadh col 255 = 0 so it never leaks; dadh row 255 = 0 -> Xn node 255 = 0.
template <int KP, bool OUTF32>
__global__ __launch_bounds__(256, 4) void fused_layer(
        const f16* __restrict__ X,      // [512][256][KP], zero-padded
        const f16* __restrict__ Wt,     // [ntiles*64][KP], zero-padded
        const float* __restrict__ bias, // [Nout] f32
        const f16* __restrict__ dadh,   // [256][256]
        void* __restrict__ Xn_,         // f16 [512][256][SN]  (or f32 [512][255][2] if OUTF32)
        int Nout, int SN) {
    __shared__ _Float16 T[64 * TSS];
    const int b = blockIdx.x;
    const int n0 = blockIdx.y * 64;
    const int tid = threadIdx.x;
    const int w = tid >> 6;
    const int ln = tid & 15;
    const int q = (tid >> 4) & 3;

    // ---- stage 1 ----
    f32x4 acc[4][4];
#pragma unroll
    for (int t = 0; t < 4; t++)
#pragma unroll
        for (int c = 0; c < 4; c++) acc[t][c] = (f32x4){0.f, 0.f, 0.f, 0.f};

    const f16* xb = X + (size_t)b * 256 * KP;
#pragma unroll 4
    for (int k = 0; k < KP; k += 32) {
        h8 af[4], bf[4];
#pragma unroll
        for (int t = 0; t < 4; t++)
            af[t] = *(const h8*)(xb + (size_t)(64 * w + 16 * t + ln) * KP + k + q * 8);
#pragma unroll
        for (int c = 0; c < 4; c++)
            bf[c] = *(const h8*)(Wt + (size_t)(n0 + 16 * c + ln) * KP + k + q * 8);
#pragma unroll
        for (int t = 0; t < 4; t++)
#pragma unroll
            for (int c = 0; c < 4; c++)
                acc[t][c] = __builtin_amdgcn_mfma_f32_16x16x32_f16(af[t], bf[c], acc[t][c], 0, 0, 0);
    }

    // bias + pack to T[feat][node]; lane holds 4 consecutive nodes -> b64 writes
#pragma unroll
    for (int c = 0; c < 4; c++) {
        int fl = 16 * c + ln;
        int gf = n0 + fl;
        float bv = (gf < Nout) ? bias[gf] : 0.f;
#pragma unroll
        for (int t = 0; t < 4; t++) {
            h4 pk;
#pragma unroll
            for (int rg = 0; rg < 4; rg++) pk[rg] = (_Float16)(acc[t][c][rg] + bv);
            *(h4*)&T[fl * TSS + 64 * w + 16 * t + q * 4] = pk;
        }
    }
    __syncthreads();

    // ---- stage 2 ----
    f32x4 acc2[4][4];
#pragma unroll
    for (int f = 0; f < 4; f++)
#pragma unroll
        for (int t = 0; t < 4; t++) acc2[f][t] = (f32x4){0.f, 0.f, 0.f, 0.f};

#pragma unroll 4
    for (int k = 0; k < 256; k += 32) {
        h8 a2[4], b2[4];
#pragma unroll
        for (int f = 0; f < 4; f++)
            a2[f] = *(const h8*)&T[(16 * f + ln) * TSS + k + q * 8];
#pragma unroll
        for (int t = 0; t < 4; t++)
            b2[t] = *(const h8*)(dadh + (size_t)(64 * w + 16 * t + ln) * 256 + k + q * 8);
#pragma unroll
        for (int f = 0; f < 4; f++)
#pragma unroll
            for (int t = 0; t < 4; t++)
                acc2[f][t] = __builtin_amdgcn_mfma_f32_16x16x32_f16(a2[f], b2[t], acc2[f][t], 0, 0, 0);
    }

    if (!OUTF32) {
        // relu, pack 4 consecutive feats, 8-B stores
        f16* xn = (f16*)Xn_ + (size_t)b * 256 * SN;
#pragma unroll
        for (int f = 0; f < 4; f++) {
            int fb = n0 + 16 * f + q * 4;
            if (fb >= SN) continue;
#pragma unroll
            for (int t = 0; t < 4; t++) {
                int node = 64 * w + 16 * t + ln;
                h4 pk;
#pragma unroll
                for (int rg = 0; rg < 4; rg++) pk[rg] = (_Float16)fmaxf(acc2[f][t][rg], 0.f);
                *(h4*)(xn + (size_t)node * SN + fb) = pk;
            }
        }
    } else {
        // final layer: feats 0,1 live in f=0, q=0, rg=0..1; f32 compact store
        if (q == 0) {
            float* op = (float*)Xn_;
#pragma unroll
            for (int t = 0; t < 4; t++) {
                int node = 64 * w + 16 * t + ln;
                if (node < NN) {
                    float2 v;
                    v.x = fmaxf(acc2[0][t][0], 0.f);
                    v.y = fmaxf(acc2[0][t][1], 0.f);
                    *(float2*)(op + ((size_t)b * NN + node) * 2) = v;
                }
            }
        }
    }
}

// ---------------- launcher ----------------

extern "C" void kernel_launch(void* const* d_in, const int* in_sizes, int n_in,
                              void* d_out, int out_size, void* d_ws, size_t ws_size,
                              hipStream_t stream) {
    const float* H   = (const float*)d_in[0];
    const float* W[6]  = {(const float*)d_in[3], (const float*)d_in[5], (const float*)d_in[7],
                          (const float*)d_in[9], (const float*)d_in[11], (const float*)d_in[13]};
    const float* Bv[6] = {(const float*)d_in[4], (const float*)d_in[6], (const float*)d_in[8],
                          (const float*)d_in[10], (const float*)d_in[12], (const float*)d_in[14]};
    const int* smi = (const int*)d_in[15];
    const int* spi = (const int*)d_in[16];

    char* p = (char*)d_ws;
    f16* bufA = (f16*)p;            p += 109051904;   // [512][256][416]  (X0, X2, X4)
    f16* bufB = (f16*)p;            p += 83886080;    // [512][256][320]  (X1, X3)
    float* dadsm = (float*)p;       p += 261120;      // [255][256] f32
    float* dadsp = (float*)p;       p += 261120;
    f16* dadhsm = (f16*)p;          p += 131072;      // [256][256] f16
    f16* dadhsp = (f16*)p;          p += 131072;
    f16* Wt0 = (f16*)p;             p += 28672;       // [448][32]
    f16* Wt1 = (f16*)p;             p += 266240;      // [320][416]
    f16* Wt2 = (f16*)p;             p += 81920;       // [128][320]
    f16* Wt3 = (f16*)p;             p += 81920;       // [320][128]
    f16* Wt4 = (f16*)p;             p += 286720;      // [448][320]
    f16* Wt5 = (f16*)p;             p += 53248;       // [64][416]
    f16* Hp  = (f16*)p;             p += 4194304;     // [512][256][32]

    // ---- build DAD + weight conversion + H packing ----
    zero_k<<<510, 256, 0, stream>>>(dadsm, 2 * NN * 256);
    scatter_k<<<10, 256, 0, stream>>>(smi, (const float*)d_in[1], dadsm, 2550);
    scatter_k<<<10, 256, 0, stream>>>(spi, (const float*)d_in[2], dadsp, 2550);
    convert_dad<<<512, 256, 0, stream>>>(dadsm, dadhsm);
    convert_wt<<<448, 256, 0, stream>>>(W[0], Wt0, 2, 400, 32);
    convert_wt<<<320, 256, 0, stream>>>(W[1], Wt1, 400, 300, 416);
    convert_wt<<<128, 256, 0, stream>>>(W[2], Wt2, 300, 100, 320);
    convert_wt<<<320, 256, 0, stream>>>(W[3], Wt3, 100, 300, 128);
    convert_wt<<<448, 256, 0, stream>>>(W[4], Wt4, 300, 400, 320);
    convert_wt<<<64, 256, 0, stream>>>(W[5], Wt5, 400, 2, 416);
    pack_h<<<512, 256, 0, stream>>>(H, Hp);

    // ---- six uniform fused layers: X_{i+1} = relu(DAD @ (X_i W + b)) ----
    // L0 enc0 (2->400)
    fused_layer<32, false><<<dim3(BB, 7), 256, 0, stream>>>(Hp, Wt0, Bv[0], dadhsm, bufA, 400, 416);
    // L1 enc1 (400->300)
    fused_layer<416, false><<<dim3(BB, 5), 256, 0, stream>>>(bufA, Wt1, Bv[1], dadhsm, bufB, 300, 320);
    // L2 enc2 (300->100)
    fused_layer<320, false><<<dim3(BB, 2), 256, 0, stream>>>(bufB, Wt2, Bv[2], dadhsm, bufA, 100, 128);
    // L3 dec0 (100->300)
    fused_layer<128, false><<<dim3(BB, 5), 256, 0, stream>>>(bufA, Wt3, Bv[3], dadhsp, bufB, 300, 320);
    // L4 dec1 (300->400)
    fused_layer<320, false><<<dim3(BB, 7), 256, 0, stream>>>(bufB, Wt4, Bv[4], dadhsp, bufA, 400, 416);
    // L5 dec2 (400->2), writes f32 d_out compact
    fused_layer<416, true><<<dim3(BB, 1), 256, 0, stream>>>(bufA, Wt5, Bv[5], dadhsp, d_out, 2, 2);
}

// Round 6
// 417.166 us; speedup vs baseline: 2.1977x; 1.6828x over previous
//
#include <hip/hip_runtime.h>
#include <hip/hip_fp16.h>

typedef __half f16;
typedef _Float16 h8 __attribute__((ext_vector_type(8)));
typedef _Float16 h4 __attribute__((ext_vector_type(4)));
typedef float f32x4 __attribute__((ext_vector_type(4)));

#define NN 255          // real nodes
#define BB 512          // batch
#define TSS 264         // T LDS row stride in f16

static __device__ __forceinline__ f16 f2h(float x) { return __float2half(x); }

// ---------------- setup kernels (tiny, one-time) ----------------

__global__ void zero_k(float* p, int n) {
    int i = blockIdx.x * 256 + threadIdx.x;
    if (i < n) p[i] = 0.f;
}

__global__ void scatter_k(const int* __restrict__ idx, const float* __restrict__ vals,
                          float* __restrict__ dad, int nnz) {
    int t = blockIdx.x * 256 + threadIdx.x;
    if (t < nnz) atomicAdd(&dad[idx[2 * t] * 256 + idx[2 * t + 1]], vals[t]);
}

// dadp[k/8][node][8] = DAD[node][k] as f16; node 255 row zero, col 255 zero by construction
__global__ void convert_dad(const float* __restrict__ dadf, f16* __restrict__ dadp) {
    int i = blockIdx.x * 256 + threadIdx.x;   // over 2*65536
    int which = i >> 16, rc = i & 65535;
    int node = rc >> 8, k = rc & 255;
    float v = (node < NN) ? dadf[(size_t)which * NN * 256 + rc] : 0.f;
    dadp[(size_t)which * 65536 + (((k >> 3) * 256 + node) << 3) + (k & 7)] = f2h(v);
}

// Wtp[tile][k/8][feat(64)][8] = W[k][feat], zero-padded (feats >= N, k >= K)
__global__ void convert_wt(const float* __restrict__ W, f16* __restrict__ Wtp,
                           int K, int N, int KPB) {
    int f = blockIdx.x;                 // padded feat index (ntiles*64 blocks)
    int tile = f >> 6, fl = f & 63;
    int Kpad = KPB * 8;
    for (int k = threadIdx.x; k < Kpad; k += 256) {
        float v = (f < N && k < K) ? W[(size_t)k * N + f] : 0.f;
        Wtp[((((size_t)tile * KPB + (k >> 3)) * 64 + fl) << 3) + (k & 7)] = f2h(v);
    }
}

// Hp[b][kb(4)][node][8]: kb0 slots 0,1 = H[b][node][0..1], everything else 0
__global__ __launch_bounds__(256) void pack_h(const float* __restrict__ H, f16* __restrict__ Hp) {
    int g = blockIdx.x * 256 + threadIdx.x;   // over 131072
    int b = g >> 8, node = g & 255;
    h8 z;
#pragma unroll
    for (int i = 0; i < 8; i++) z[i] = (_Float16)0.f;
    h8 h0 = z;
    if (node < NN) {
        h0[0] = (_Float16)H[((size_t)b * NN + node) * 2];
        h0[1] = (_Float16)H[((size_t)b * NN + node) * 2 + 1];
    }
    _Float16* base = (_Float16*)Hp + (size_t)b * 4 * 2048;
    *(h8*)(base + ((0 * 256 + node) << 3)) = h0;
    *(h8*)(base + ((1 * 256 + node) << 3)) = z;
    *(h8*)(base + ((2 * 256 + node) << 3)) = z;
    *(h8*)(base + ((3 * 256 + node) << 3)) = z;
}

// ============ fused layer: Xn = relu( DAD @ (X@W + bias) ), one (b, 64-feat tile) per block ============
// All global fragment sources in k-panel layout [..][k/8][row][8] -> 64-lane loads are 4x256B segments.
// Stage 1 (no barrier): T[64 feat][256 node] = (X[b] @ W_tile)^T + bias, frags from global.
// Stage 2 (no barrier): out = DAD @ T, A-op from LDS T, B-op dadp from global.
// One __syncthreads total.
template <int KPB, bool OUTF32>
__global__ __launch_bounds__(256, 4) void fused_layer(
        const f16* __restrict__ X,      // [512][KPB][256][8] zero-padded
        const f16* __restrict__ Wtp,    // [ntiles][KPB][64][8] zero-padded
        const float* __restrict__ bias, // [Nout] f32
        const f16* __restrict__ dadp,   // [32][256][8]
        void* __restrict__ Xn_,         // f16 [512][SN/8][256][8]  (or f32 [512][255][2] if OUTF32)
        int Nout, int SN) {
    __shared__ _Float16 T[64 * TSS];
    const int b = blockIdx.x;
    const int tile = blockIdx.y;
    const int n0 = tile * 64;
    const int tid = threadIdx.x;
    const int w = tid >> 6;
    const int ln = tid & 15;
    const int q = (tid >> 4) & 3;

    // ---- stage 1: wave w: nodes 64w..64w+63 (4 A-tiles) x 64 feats (4 B-tiles) ----
    f32x4 acc[4][4];
#pragma unroll
    for (int t = 0; t < 4; t++)
#pragma unroll
        for (int c = 0; c < 4; c++) acc[t][c] = (f32x4){0.f, 0.f, 0.f, 0.f};

    const f16* xb = X + (size_t)b * KPB * 2048;
    const f16* wp = Wtp + (size_t)tile * KPB * 512;
#pragma unroll 4
    for (int kb = 0; kb < KPB; kb += 4) {
        h8 af[4], bf[4];
#pragma unroll
        for (int t = 0; t < 4; t++)
            af[t] = *(const h8*)(xb + (((kb + q) * 256 + 64 * w + 16 * t + ln) << 3));
#pragma unroll
        for (int c = 0; c < 4; c++)
            bf[c] = *(const h8*)(wp + (((kb + q) * 64 + 16 * c + ln) << 3));
#pragma unroll
        for (int t = 0; t < 4; t++)
#pragma unroll
            for (int c = 0; c < 4; c++)
                acc[t][c] = __builtin_amdgcn_mfma_f32_16x16x32_f16(af[t], bf[c], acc[t][c], 0, 0, 0);
    }

    // bias + pack to T[feat][node]; lane holds 4 consecutive nodes -> b64 writes
#pragma unroll
    for (int c = 0; c < 4; c++) {
        int fl = 16 * c + ln;
        int gf = n0 + fl;
        float bv = (gf < Nout) ? bias[gf] : 0.f;
#pragma unroll
        for (int t = 0; t < 4; t++) {
            h4 pk;
#pragma unroll
            for (int rg = 0; rg < 4; rg++) pk[rg] = (_Float16)(acc[t][c][rg] + bv);
            *(h4*)&T[fl * TSS + 64 * w + 16 * t + q * 4] = pk;
        }
    }
    __syncthreads();

    // ---- stage 2: wave w: 64 feats (A-op from T) x node_outs 64w..64w+63 (4 B-tiles) ----
    f32x4 acc2[4][4];
#pragma unroll
    for (int f = 0; f < 4; f++)
#pragma unroll
        for (int t = 0; t < 4; t++) acc2[f][t] = (f32x4){0.f, 0.f, 0.f, 0.f};

#pragma unroll 4
    for (int kb = 0; kb < 32; kb += 4) {
        h8 a2[4], b2[4];
#pragma unroll
        for (int f = 0; f < 4; f++)
            a2[f] = *(const h8*)&T[(16 * f + ln) * TSS + (kb + q) * 8];
#pragma unroll
        for (int t = 0; t < 4; t++)
            b2[t] = *(const h8*)(dadp + (((kb + q) * 256 + 64 * w + 16 * t + ln) << 3));
#pragma unroll
        for (int f = 0; f < 4; f++)
#pragma unroll
            for (int t = 0; t < 4; t++)
                acc2[f][t] = __builtin_amdgcn_mfma_f32_16x16x32_f16(a2[f], b2[t], acc2[f][t], 0, 0, 0);
    }

    if (!OUTF32) {
        // relu; store into next layer's k-panel layout: 8-B stores, 16 lanes at 16-B stride
        f16* xn = (f16*)Xn_ + (size_t)b * (SN >> 3) * 2048;
#pragma unroll
        for (int f = 0; f < 4; f++) {
            int fb = n0 + 16 * f + q * 4;     // 4 consecutive feats
            if (fb >= SN) continue;
            int fb8 = fb >> 3, off = fb & 7;  // off in {0,4}
#pragma unroll
            for (int t = 0; t < 4; t++) {
                int node = 64 * w + 16 * t + ln;
                h4 pk;
#pragma unroll
                for (int rg = 0; rg < 4; rg++) pk[rg] = (_Float16)fmaxf(acc2[f][t][rg], 0.f);
                *(h4*)(xn + (((size_t)fb8 * 256 + node) << 3) + off) = pk;
            }
        }
    } else {
        // final layer: feats 0,1 live in f=0, q=0, rg=0..1; f32 compact store
        if (q == 0) {
            float* op = (float*)Xn_;
#pragma unroll
            for (int t = 0; t < 4; t++) {
                int node = 64 * w + 16 * t + ln;
                if (node < NN) {
                    float2 v;
                    v.x = fmaxf(acc2[0][t][0], 0.f);
                    v.y = fmaxf(acc2[0][t][1], 0.f);
                    *(float2*)(op + ((size_t)b * NN + node) * 2) = v;
                }
            }
        }
    }
}

// ---------------- launcher ----------------

extern "C" void kernel_launch(void* const* d_in, const int* in_sizes, int n_in,
                              void* d_out, int out_size, void* d_ws, size_t ws_size,
                              hipStream_t stream) {
    const float* H   = (const float*)d_in[0];
    const float* W[6]  = {(const float*)d_in[3], (const float*)d_in[5], (const float*)d_in[7],
                          (const float*)d_in[9], (const float*)d_in[11], (const float*)d_in[13]};
    const float* Bv[6] = {(const float*)d_in[4], (const float*)d_in[6], (const float*)d_in[8],
                          (const float*)d_in[10], (const float*)d_in[12], (const float*)d_in[14]};
    const int* smi = (const int*)d_in[15];
    const int* spi = (const int*)d_in[16];

    char* p = (char*)d_ws;
    f16* bufA = (f16*)p;            p += 109051904;   // [512][52][256][8]  (X0, X2, X4)
    f16* bufB = (f16*)p;            p += 83886080;    // [512][40][256][8]  (X1, X3)
    float* dadsm = (float*)p;       p += 261120;      // [255][256] f32
    float* dadsp = (float*)p;       p += 261120;
    f16* dadpsm = (f16*)p;          p += 131072;      // [32][256][8] f16 k-panel
    f16* dadpsp = (f16*)p;          p += 131072;
    f16* Wt0 = (f16*)p;             p += 28672;       // [7][4][64][8]
    f16* Wt1 = (f16*)p;             p += 266240;      // [5][52][64][8]
    f16* Wt2 = (f16*)p;             p += 81920;       // [2][40][64][8]
    f16* Wt3 = (f16*)p;             p += 81920;       // [5][16][64][8]
    f16* Wt4 = (f16*)p;             p += 286720;      // [7][40][64][8]
    f16* Wt5 = (f16*)p;             p += 53248;       // [1][52][64][8]
    f16* Hp  = (f16*)p;             p += 4194304;     // [512][4][256][8]

    // ---- build DAD + weight conversion + H packing ----
    zero_k<<<510, 256, 0, stream>>>(dadsm, 2 * NN * 256);
    scatter_k<<<10, 256, 0, stream>>>(smi, (const float*)d_in[1], dadsm, 2550);
    scatter_k<<<10, 256, 0, stream>>>(spi, (const float*)d_in[2], dadsp, 2550);
    convert_dad<<<512, 256, 0, stream>>>(dadsm, dadpsm);
    convert_wt<<<448, 256, 0, stream>>>(W[0], Wt0, 2, 400, 4);
    convert_wt<<<320, 256, 0, stream>>>(W[1], Wt1, 400, 300, 52);
    convert_wt<<<128, 256, 0, stream>>>(W[2], Wt2, 300, 100, 40);
    convert_wt<<<320, 256, 0, stream>>>(W[3], Wt3, 100, 300, 16);
    convert_wt<<<448, 256, 0, stream>>>(W[4], Wt4, 300, 400, 40);
    convert_wt<<<64, 256, 0, stream>>>(W[5], Wt5, 400, 2, 52);
    pack_h<<<512, 256, 0, stream>>>(H, Hp);

    // ---- six uniform fused layers: X_{i+1} = relu(DAD @ (X_i W + b)) ----
    fused_layer<4,  false><<<dim3(BB, 7), 256, 0, stream>>>(Hp,   Wt0, Bv[0], dadpsm, bufA, 400, 416);
    fused_layer<52, false><<<dim3(BB, 5), 256, 0, stream>>>(bufA, Wt1, Bv[1], dadpsm, bufB, 300, 320);
    fused_layer<40, false><<<dim3(BB, 2), 256, 0, stream>>>(bufB, Wt2, Bv[2], dadpsm, bufA, 100, 128);
    fused_layer<16, false><<<dim3(BB, 5), 256, 0, stream>>>(bufA, Wt3, Bv[3], dadpsp, bufB, 300, 320);
    fused_layer<40, false><<<dim3(BB, 7), 256, 0, stream>>>(bufB, Wt4, Bv[4], dadpsp, bufA, 400, 416);
    fused_layer<52, true ><<<dim3(BB, 1), 256, 0, stream>>>(bufA, Wt5, Bv[5], dadpsp, d_out, 2, 2);
}

// Round 7
// 379.674 us; speedup vs baseline: 2.4147x; 1.0987x over previous
//
#include <hip/hip_runtime.h>
#include <hip/hip_fp16.h>

typedef __half f16;
typedef _Float16 h8 __attribute__((ext_vector_type(8)));
typedef _Float16 h4 __attribute__((ext_vector_type(4)));
typedef float f32x4 __attribute__((ext_vector_type(4)));

#define NN 255          // real nodes
#define BB 512          // batch
#define TSS 264         // T LDS row stride in f16

static __device__ __forceinline__ f16 f2h(float x) { return __float2half(x); }

// ---------------- setup kernels (tiny, one-time) ----------------

__global__ void zero_k(float* p, int n) {
    int i = blockIdx.x * 256 + threadIdx.x;
    if (i < n) p[i] = 0.f;
}

__global__ void scatter_k(const int* __restrict__ idx, const float* __restrict__ vals,
                          float* __restrict__ dad, int nnz) {
    int t = blockIdx.x * 256 + threadIdx.x;
    if (t < nnz) atomicAdd(&dad[idx[2 * t] * 256 + idx[2 * t + 1]], vals[t]);
}

// dadp[k/8][node][8] = DAD[node][k] as f16; node 255 row zero, col 255 zero by construction
__global__ void convert_dad(const float* __restrict__ dadf, f16* __restrict__ dadp) {
    int i = blockIdx.x * 256 + threadIdx.x;   // over 2*65536
    int which = i >> 16, rc = i & 65535;
    int node = rc >> 8, k = rc & 255;
    float v = (node < NN) ? dadf[(size_t)which * NN * 256 + rc] : 0.f;
    dadp[(size_t)which * 65536 + (((k >> 3) * 256 + node) << 3) + (k & 7)] = f2h(v);
}

// Wtp[tile][k/8][feat(64)][8] = W[k][feat], zero-padded (feats >= N, k >= K)
__global__ void convert_wt(const float* __restrict__ W, f16* __restrict__ Wtp,
                           int K, int N, int KPB) {
    int f = blockIdx.x;                 // padded feat index (ntiles*64 blocks)
    int tile = f >> 6, fl = f & 63;
    int Kpad = KPB * 8;
    for (int k = threadIdx.x; k < Kpad; k += 256) {
        float v = (f < N && k < K) ? W[(size_t)k * N + f] : 0.f;
        Wtp[((((size_t)tile * KPB + (k >> 3)) * 64 + fl) << 3) + (k & 7)] = f2h(v);
    }
}

// Hp[b][kb(4)][node][8]: kb0 slots 0,1 = H[b][node][0..1], everything else 0
__global__ __launch_bounds__(256) void pack_h(const float* __restrict__ H, f16* __restrict__ Hp) {
    int g = blockIdx.x * 256 + threadIdx.x;   // over 131072
    int b = g >> 8, node = g & 255;
    h8 z;
#pragma unroll
    for (int i = 0; i < 8; i++) z[i] = (_Float16)0.f;
    h8 h0 = z;
    if (node < NN) {
        h0[0] = (_Float16)H[((size_t)b * NN + node) * 2];
        h0[1] = (_Float16)H[((size_t)b * NN + node) * 2 + 1];
    }
    _Float16* base = (_Float16*)Hp + (size_t)b * 4 * 2048;
    *(h8*)(base + ((0 * 256 + node) << 3)) = h0;
    *(h8*)(base + ((1 * 256 + node) << 3)) = z;
    *(h8*)(base + ((2 * 256 + node) << 3)) = z;
    *(h8*)(base + ((3 * 256 + node) << 3)) = z;
}

// ============ fused layer: Xn = relu( DAD @ (X@W + bias) ) ============
// 1D grid, XCD-aware: id = 8*((b%64)*ntiles + tile) + b/64  ->  all feat-tiles of one b run
// back-to-back on one XCD (id%8) so X[b] stays L2-resident across tiles.
// Stage 1 (no barrier): T[64 feat][256 node] = (X[b] @ W_tile)^T + bias, frags from global,
//   1-deep double-buffered prefetch. Stage 2 (no barrier): out = DAD @ T, A from LDS, B (dadp)
//   from global with prefetch. One __syncthreads total.
template <int KPB, bool OUTF32>
__global__ __launch_bounds__(256, 3) void fused_layer(
        const f16* __restrict__ X,      // [512][KPB][256][8] zero-padded
        const f16* __restrict__ Wtp,    // [ntiles][KPB][64][8] zero-padded
        const float* __restrict__ bias, // [Nout] f32
        const f16* __restrict__ dadp,   // [32][256][8]
        void* __restrict__ Xn_,         // f16 [512][SN/8][256][8]  (or f32 [512][255][2] if OUTF32)
        int Nout, int SN, int ntiles) {
    __shared__ _Float16 T[64 * TSS];
    const int id = blockIdx.x;
    const int s = id >> 3;
    const int bq = s / ntiles;
    const int b = ((id & 7) << 6) + bq;
    const int tile = s - bq * ntiles;
    const int n0 = tile * 64;
    const int tid = threadIdx.x;
    const int w = tid >> 6;
    const int ln = tid & 15;
    const int q = (tid >> 4) & 3;

    // ---- stage 1: wave w: nodes 64w..64w+63 (4 A-tiles) x 64 feats (4 B-tiles) ----
    f32x4 acc[4][4];
#pragma unroll
    for (int t = 0; t < 4; t++)
#pragma unroll
        for (int c = 0; c < 4; c++) acc[t][c] = (f32x4){0.f, 0.f, 0.f, 0.f};

    const f16* xb = X + (size_t)b * KPB * 2048;
    const f16* wp = Wtp + (size_t)tile * KPB * 512;

    h8 af[2][4], bf[2][4];
#pragma unroll
    for (int t = 0; t < 4; t++)
        af[0][t] = *(const h8*)(xb + ((q * 256 + 64 * w + 16 * t + ln) << 3));
#pragma unroll
    for (int c = 0; c < 4; c++)
        bf[0][c] = *(const h8*)(wp + ((q * 64 + 16 * c + ln) << 3));

#pragma unroll
    for (int kb = 0; kb < KPB; kb += 4) {
        const int cur = (kb >> 2) & 1, nxt = cur ^ 1;
        if (kb + 4 < KPB) {
#pragma unroll
            for (int t = 0; t < 4; t++)
                af[nxt][t] = *(const h8*)(xb + (((kb + 4 + q) * 256 + 64 * w + 16 * t + ln) << 3));
#pragma unroll
            for (int c = 0; c < 4; c++)
                bf[nxt][c] = *(const h8*)(wp + (((kb + 4 + q) * 64 + 16 * c + ln) << 3));
        }
#pragma unroll
        for (int t = 0; t < 4; t++)
#pragma unroll
            for (int c = 0; c < 4; c++)
                acc[t][c] = __builtin_amdgcn_mfma_f32_16x16x32_f16(af[cur][t], bf[cur][c], acc[t][c], 0, 0, 0);
    }

    // bias + pack to T[feat][node]; lane holds 4 consecutive nodes -> b64 writes
#pragma unroll
    for (int c = 0; c < 4; c++) {
        int fl = 16 * c + ln;
        int gf = n0 + fl;
        float bv = (gf < Nout) ? bias[gf] : 0.f;
#pragma unroll
        for (int t = 0; t < 4; t++) {
            h4 pk;
#pragma unroll
            for (int rg = 0; rg < 4; rg++) pk[rg] = (_Float16)(acc[t][c][rg] + bv);
            *(h4*)&T[fl * TSS + 64 * w + 16 * t + q * 4] = pk;
        }
    }
    __syncthreads();

    // ---- stage 2: wave w: 64 feats (A-op from T) x node_outs 64w..64w+63 (4 B-tiles) ----
    f32x4 acc2[4][4];
#pragma unroll
    for (int f = 0; f < 4; f++)
#pragma unroll
        for (int t = 0; t < 4; t++) acc2[f][t] = (f32x4){0.f, 0.f, 0.f, 0.f};

    h8 b2[2][4];
#pragma unroll
    for (int t = 0; t < 4; t++)
        b2[0][t] = *(const h8*)(dadp + ((q * 256 + 64 * w + 16 * t + ln) << 3));

#pragma unroll
    for (int kb = 0; kb < 32; kb += 4) {
        const int cur = (kb >> 2) & 1, nxt = cur ^ 1;
        if (kb + 4 < 32) {
#pragma unroll
            for (int t = 0; t < 4; t++)
                b2[nxt][t] = *(const h8*)(dadp + (((kb + 4 + q) * 256 + 64 * w + 16 * t + ln) << 3));
        }
        h8 a2[4];
#pragma unroll
        for (int f = 0; f < 4; f++)
            a2[f] = *(const h8*)&T[(16 * f + ln) * TSS + (kb + q) * 8];
#pragma unroll
        for (int f = 0; f < 4; f++)
#pragma unroll
            for (int t = 0; t < 4; t++)
                acc2[f][t] = __builtin_amdgcn_mfma_f32_16x16x32_f16(a2[f], b2[cur][t], acc2[f][t], 0, 0, 0);
    }

    if (!OUTF32) {
        // relu; store into next layer's k-panel layout (2x256B segments per store inst)
        f16* xn = (f16*)Xn_ + (size_t)b * (SN >> 3) * 2048;
#pragma unroll
        for (int f = 0; f < 4; f++) {
            int fb = n0 + 16 * f + q * 4;     // 4 consecutive feats
            if (fb >= SN) continue;
            int fb8 = fb >> 3, off = fb & 7;  // off in {0,4}
#pragma unroll
            for (int t = 0; t < 4; t++) {
                int node = 64 * w + 16 * t + ln;
                h4 pk;
#pragma unroll
                for (int rg = 0; rg < 4; rg++) pk[rg] = (_Float16)fmaxf(acc2[f][t][rg], 0.f);
                *(h4*)(xn + (((size_t)fb8 * 256 + node) << 3) + off) = pk;
            }
        }
    } else {
        // final layer: feats 0,1 live in f=0, q=0, rg=0..1; f32 compact store
        if (q == 0) {
            float* op = (float*)Xn_;
#pragma unroll
            for (int t = 0; t < 4; t++) {
                int node = 64 * w + 16 * t + ln;
                if (node < NN) {
                    float2 v;
                    v.x = fmaxf(acc2[0][t][0], 0.f);
                    v.y = fmaxf(acc2[0][t][1], 0.f);
                    *(float2*)(op + ((size_t)b * NN + node) * 2) = v;
                }
            }
        }
    }
}

// ---------------- launcher ----------------

extern "C" void kernel_launch(void* const* d_in, const int* in_sizes, int n_in,
                              void* d_out, int out_size, void* d_ws, size_t ws_size,
                              hipStream_t stream) {
    const float* H   = (const float*)d_in[0];
    const float* W[6]  = {(const float*)d_in[3], (const float*)d_in[5], (const float*)d_in[7],
                          (const float*)d_in[9], (const float*)d_in[11], (const float*)d_in[13]};
    const float* Bv[6] = {(const float*)d_in[4], (const float*)d_in[6], (const float*)d_in[8],
                          (const float*)d_in[10], (const float*)d_in[12], (const float*)d_in[14]};
    const int* smi = (const int*)d_in[15];
    const int* spi = (const int*)d_in[16];

    char* p = (char*)d_ws;
    f16* bufA = (f16*)p;            p += 109051904;   // [512][52][256][8]  (X0, X2, X4)
    f16* bufB = (f16*)p;            p += 83886080;    // [512][40][256][8]  (X1, X3)
    float* dadsm = (float*)p;       p += 261120;      // [255][256] f32
    float* dadsp = (float*)p;       p += 261120;
    f16* dadpsm = (f16*)p;          p += 131072;      // [32][256][8] f16 k-panel
    f16* dadpsp = (f16*)p;          p += 131072;
    f16* Wt0 = (f16*)p;             p += 28672;       // [7][4][64][8]
    f16* Wt1 = (f16*)p;             p += 266240;      // [5][52][64][8]
    f16* Wt2 = (f16*)p;             p += 81920;       // [2][40][64][8]
    f16* Wt3 = (f16*)p;             p += 81920;       // [5][16][64][8]
    f16* Wt4 = (f16*)p;             p += 286720;      // [7][40][64][8]
    f16* Wt5 = (f16*)p;             p += 53248;       // [1][52][64][8]
    f16* Hp  = (f16*)p;             p += 4194304;     // [512][4][256][8]

    // ---- build DAD + weight conversion + H packing ----
    zero_k<<<510, 256, 0, stream>>>(dadsm, 2 * NN * 256);
    scatter_k<<<10, 256, 0, stream>>>(smi, (const float*)d_in[1], dadsm, 2550);
    scatter_k<<<10, 256, 0, stream>>>(spi, (const float*)d_in[2], dadsp, 2550);
    convert_dad<<<512, 256, 0, stream>>>(dadsm, dadpsm);
    convert_wt<<<448, 256, 0, stream>>>(W[0], Wt0, 2, 400, 4);
    convert_wt<<<320, 256, 0, stream>>>(W[1], Wt1, 400, 300, 52);
    convert_wt<<<128, 256, 0, stream>>>(W[2], Wt2, 300, 100, 40);
    convert_wt<<<320, 256, 0, stream>>>(W[3], Wt3, 100, 300, 16);
    convert_wt<<<448, 256, 0, stream>>>(W[4], Wt4, 300, 400, 40);
    convert_wt<<<64, 256, 0, stream>>>(W[5], Wt5, 400, 2, 52);
    pack_h<<<512, 256, 0, stream>>>(H, Hp);

    // ---- six uniform fused layers: X_{i+1} = relu(DAD @ (X_i W + b)) ----
    fused_layer<4,  false><<<BB * 7, 256, 0, stream>>>(Hp,   Wt0, Bv[0], dadpsm, bufA, 400, 416, 7);
    fused_layer<52, false><<<BB * 5, 256, 0, stream>>>(bufA, Wt1, Bv[1], dadpsm, bufB, 300, 320, 5);
    fused_layer<40, false><<<BB * 2, 256, 0, stream>>>(bufB, Wt2, Bv[2], dadpsm, bufA, 100, 128, 2);
    fused_layer<16, false><<<BB * 5, 256, 0, stream>>>(bufA, Wt3, Bv[3], dadpsp, bufB, 300, 320, 5);
    fused_layer<40, false><<<BB * 7, 256, 0, stream>>>(bufB, Wt4, Bv[4], dadpsp, bufA, 400, 416, 7);
    fused_layer<52, true ><<<BB * 1, 256, 0, stream>>>(bufA, Wt5, Bv[5], dadpsp, d_out, 2, 2, 1);
}

// Round 8
// 359.647 us; speedup vs baseline: 2.5492x; 1.0557x over previous
//
#include <hip/hip_runtime.h>
#include <hip/hip_fp16.h>

typedef __half f16;
typedef _Float16 h8 __attribute__((ext_vector_type(8)));
typedef _Float16 h4 __attribute__((ext_vector_type(4)));
typedef float f32x4 __attribute__((ext_vector_type(4)));

#define NN 255          // real nodes
#define BB 512          // batch
#define TSS 264         // T LDS row stride in f16

static __device__ __forceinline__ f16 f2h(float x) { return __float2half(x); }

// ---------------- setup kernels (tiny, one-time) ----------------

__global__ void zero_k(float* p, int n) {
    int i = blockIdx.x * 256 + threadIdx.x;
    if (i < n) p[i] = 0.f;
}

__global__ void scatter_k(const int* __restrict__ idx, const float* __restrict__ vals,
                          float* __restrict__ dad, int nnz) {
    int t = blockIdx.x * 256 + threadIdx.x;
    if (t < nnz) atomicAdd(&dad[idx[2 * t] * 256 + idx[2 * t + 1]], vals[t]);
}

// dadp[k/8][node][8] = DAD[node][k] as f16; node 255 row zero, col 255 zero by construction
__global__ void convert_dad(const float* __restrict__ dadf, f16* __restrict__ dadp) {
    int i = blockIdx.x * 256 + threadIdx.x;   // over 2*65536
    int which = i >> 16, rc = i & 65535;
    int node = rc >> 8, k = rc & 255;
    float v = (node < NN) ? dadf[(size_t)which * NN * 256 + rc] : 0.f;
    dadp[(size_t)which * 65536 + (((k >> 3) * 256 + node) << 3) + (k & 7)] = f2h(v);
}

// Wtp[tile][k/8][feat(64)][8] = W[k][feat], zero-padded (feats >= N, k >= K)
__global__ void convert_wt(const float* __restrict__ W, f16* __restrict__ Wtp,
                           int K, int N, int KPB) {
    int f = blockIdx.x;                 // padded feat index (ntiles*64 blocks)
    int tile = f >> 6, fl = f & 63;
    int Kpad = KPB * 8;
    for (int k = threadIdx.x; k < Kpad; k += 256) {
        float v = (f < N && k < K) ? W[(size_t)k * N + f] : 0.f;
        Wtp[((((size_t)tile * KPB + (k >> 3)) * 64 + fl) << 3) + (k & 7)] = f2h(v);
    }
}

// Hp[b][kb(4)][node][8]: kb0 slots 0,1 = H[b][node][0..1], everything else 0
__global__ __launch_bounds__(256) void pack_h(const float* __restrict__ H, f16* __restrict__ Hp) {
    int g = blockIdx.x * 256 + threadIdx.x;   // over 131072
    int b = g >> 8, node = g & 255;
    h8 z;
#pragma unroll
    for (int i = 0; i < 8; i++) z[i] = (_Float16)0.f;
    h8 h0 = z;
    if (node < NN) {
        h0[0] = (_Float16)H[((size_t)b * NN + node) * 2];
        h0[1] = (_Float16)H[((size_t)b * NN + node) * 2 + 1];
    }
    _Float16* base = (_Float16*)Hp + (size_t)b * 4 * 2048;
    *(h8*)(base + ((0 * 256 + node) << 3)) = h0;
    *(h8*)(base + ((1 * 256 + node) << 3)) = z;
    *(h8*)(base + ((2 * 256 + node) << 3)) = z;
    *(h8*)(base + ((3 * 256 + node) << 3)) = z;
}

// ============ fused layer: Xn = relu( DAD @ (X@W + bias) ) ============
// 1D grid, XCD-aware: id = 8*(bq*ntiles + tile) + b/64, XCD = b>>6 every layer so readers
// land on the writer's L2. rev flips bq order per layer (LIFO): layer i+1 reads the
// most-recently-written X[b] first -> L2 hits at layer boundaries.
// Stage 1: T = (X[b] @ W_tile)^T + bias. af (X, slow path) ring-2 prefetched; bf (Wtp,
// L2-hot) in-loop with c*4-MFMA slack. Stage 2: out = DAD @ T; b2 (dadp) ring-2, a2 from LDS.
// One __syncthreads total. 4 blocks/CU.
template <int KPB, bool OUTF32>
__global__ __launch_bounds__(256, 4) void fused_layer(
        const f16* __restrict__ X,      // [512][KPB][256][8] zero-padded
        const f16* __restrict__ Wtp,    // [ntiles][KPB][64][8] zero-padded
        const float* __restrict__ bias, // [Nout] f32
        const f16* __restrict__ dadp,   // [32][256][8]
        void* __restrict__ Xn_,         // f16 [512][SN/8][256][8]  (or f32 [512][255][2] if OUTF32)
        int Nout, int SN, int ntiles, int rev) {
    __shared__ _Float16 T[64 * TSS];
    const int id = blockIdx.x;
    int s = id >> 3;
    int bq = s / ntiles;
    const int tile = s - bq * ntiles;
    if (rev) bq = 63 - bq;
    const int b = ((id & 7) << 6) + bq;
    const int n0 = tile * 64;
    const int tid = threadIdx.x;
    const int w = tid >> 6;
    const int ln = tid & 15;
    const int q = (tid >> 4) & 3;

    // ---- stage 1: wave w: nodes 64w..64w+63 (4 A-tiles) x 64 feats (4 B-tiles) ----
    f32x4 acc[4][4];
#pragma unroll
    for (int t = 0; t < 4; t++)
#pragma unroll
        for (int c = 0; c < 4; c++) acc[t][c] = (f32x4){0.f, 0.f, 0.f, 0.f};

    const f16* xb = X + (size_t)b * KPB * 2048;
    const f16* wp = Wtp + (size_t)tile * KPB * 512;

    h8 af[2][4];
#pragma unroll
    for (int t = 0; t < 4; t++)
        af[0][t] = *(const h8*)(xb + ((q * 256 + 64 * w + 16 * t + ln) << 3));

#pragma unroll
    for (int kb = 0; kb < KPB; kb += 4) {
        const int cur = (kb >> 2) & 1, nxt = cur ^ 1;
        h8 bf[4];
#pragma unroll
        for (int c = 0; c < 4; c++)
            bf[c] = *(const h8*)(wp + (((kb + q) * 64 + 16 * c + ln) << 3));
        if (kb + 4 < KPB) {
#pragma unroll
            for (int t = 0; t < 4; t++)
                af[nxt][t] = *(const h8*)(xb + (((kb + 4 + q) * 256 + 64 * w + 16 * t + ln) << 3));
        }
#pragma unroll
        for (int c = 0; c < 4; c++)
#pragma unroll
            for (int t = 0; t < 4; t++)
                acc[t][c] = __builtin_amdgcn_mfma_f32_16x16x32_f16(af[cur][t], bf[c], acc[t][c], 0, 0, 0);
    }

    // bias + pack to T[feat][node]; lane holds 4 consecutive nodes -> b64 writes
#pragma unroll
    for (int c = 0; c < 4; c++) {
        int fl = 16 * c + ln;
        int gf = n0 + fl;
        float bv = (gf < Nout) ? bias[gf] : 0.f;
#pragma unroll
        for (int t = 0; t < 4; t++) {
            h4 pk;
#pragma unroll
            for (int rg = 0; rg < 4; rg++) pk[rg] = (_Float16)(acc[t][c][rg] + bv);
            *(h4*)&T[fl * TSS + 64 * w + 16 * t + q * 4] = pk;
        }
    }
    __syncthreads();

    // ---- stage 2: wave w: 64 feats (A-op from T) x node_outs 64w..64w+63 (4 B-tiles) ----
    f32x4 acc2[4][4];
#pragma unroll
    for (int f = 0; f < 4; f++)
#pragma unroll
        for (int t = 0; t < 4; t++) acc2[f][t] = (f32x4){0.f, 0.f, 0.f, 0.f};

    h8 b2[2][4];
#pragma unroll
    for (int t = 0; t < 4; t++)
        b2[0][t] = *(const h8*)(dadp + ((q * 256 + 64 * w + 16 * t + ln) << 3));

#pragma unroll
    for (int kb = 0; kb < 32; kb += 4) {
        const int cur = (kb >> 2) & 1, nxt = cur ^ 1;
        if (kb + 4 < 32) {
#pragma unroll
            for (int t = 0; t < 4; t++)
                b2[nxt][t] = *(const h8*)(dadp + (((kb + 4 + q) * 256 + 64 * w + 16 * t + ln) << 3));
        }
        h8 a2[4];
#pragma unroll
        for (int f = 0; f < 4; f++)
            a2[f] = *(const h8*)&T[(16 * f + ln) * TSS + (kb + q) * 8];
#pragma unroll
        for (int t = 0; t < 4; t++)
#pragma unroll
            for (int f = 0; f < 4; f++)
                acc2[f][t] = __builtin_amdgcn_mfma_f32_16x16x32_f16(a2[f], b2[cur][t], acc2[f][t], 0, 0, 0);
    }

    if (!OUTF32) {
        // relu; store into next layer's k-panel layout (2x256B segments per store inst)
        f16* xn = (f16*)Xn_ + (size_t)b * (SN >> 3) * 2048;
#pragma unroll
        for (int f = 0; f < 4; f++) {
            int fb = n0 + 16 * f + q * 4;     // 4 consecutive feats
            if (fb >= SN) continue;
            int fb8 = fb >> 3, off = fb & 7;  // off in {0,4}
#pragma unroll
            for (int t = 0; t < 4; t++) {
                int node = 64 * w + 16 * t + ln;
                h4 pk;
#pragma unroll
                for (int rg = 0; rg < 4; rg++) pk[rg] = (_Float16)fmaxf(acc2[f][t][rg], 0.f);
                *(h4*)(xn + (((size_t)fb8 * 256 + node) << 3) + off) = pk;
            }
        }
    } else {
        // final layer: feats 0,1 live in f=0, q=0, rg=0..1; f32 compact store
        if (q == 0) {
            float* op = (float*)Xn_;
#pragma unroll
            for (int t = 0; t < 4; t++) {
                int node = 64 * w + 16 * t + ln;
                if (node < NN) {
                    float2 v;
                    v.x = fmaxf(acc2[0][t][0], 0.f);
                    v.y = fmaxf(acc2[0][t][1], 0.f);
                    *(float2*)(op + ((size_t)b * NN + node) * 2) = v;
                }
            }
        }
    }
}

// ---------------- launcher ----------------

extern "C" void kernel_launch(void* const* d_in, const int* in_sizes, int n_in,
                              void* d_out, int out_size, void* d_ws, size_t ws_size,
                              hipStream_t stream) {
    const float* H   = (const float*)d_in[0];
    const float* W[6]  = {(const float*)d_in[3], (const float*)d_in[5], (const float*)d_in[7],
                          (const float*)d_in[9], (const float*)d_in[11], (const float*)d_in[13]};
    const float* Bv[6] = {(const float*)d_in[4], (const float*)d_in[6], (const float*)d_in[8],
                          (const float*)d_in[10], (const float*)d_in[12], (const float*)d_in[14]};
    const int* smi = (const int*)d_in[15];
    const int* spi = (const int*)d_in[16];

    char* p = (char*)d_ws;
    f16* bufA = (f16*)p;            p += 109051904;   // [512][52][256][8]  (X0, X2, X4)
    f16* bufB = (f16*)p;            p += 83886080;    // [512][40][256][8]  (X1, X3)
    float* dadsm = (float*)p;       p += 261120;      // [255][256] f32
    float* dadsp = (float*)p;       p += 261120;
    f16* dadpsm = (f16*)p;          p += 131072;      // [32][256][8] f16 k-panel
    f16* dadpsp = (f16*)p;          p += 131072;
    f16* Wt0 = (f16*)p;             p += 28672;       // [7][4][64][8]
    f16* Wt1 = (f16*)p;             p += 266240;      // [5][52][64][8]
    f16* Wt2 = (f16*)p;             p += 81920;       // [2][40][64][8]
    f16* Wt3 = (f16*)p;             p += 81920;       // [5][16][64][8]
    f16* Wt4 = (f16*)p;             p += 286720;      // [7][40][64][8]
    f16* Wt5 = (f16*)p;             p += 53248;       // [1][52][64][8]
    f16* Hp  = (f16*)p;             p += 4194304;     // [512][4][256][8]

    // ---- build DAD + weight conversion + H packing ----
    zero_k<<<510, 256, 0, stream>>>(dadsm, 2 * NN * 256);
    scatter_k<<<10, 256, 0, stream>>>(smi, (const float*)d_in[1], dadsm, 2550);
    scatter_k<<<10, 256, 0, stream>>>(spi, (const float*)d_in[2], dadsp, 2550);
    convert_dad<<<512, 256, 0, stream>>>(dadsm, dadpsm);
    convert_wt<<<448, 256, 0, stream>>>(W[0], Wt0, 2, 400, 4);
    convert_wt<<<320, 256, 0, stream>>>(W[1], Wt1, 400, 300, 52);
    convert_wt<<<128, 256, 0, stream>>>(W[2], Wt2, 300, 100, 40);
    convert_wt<<<320, 256, 0, stream>>>(W[3], Wt3, 100, 300, 16);
    convert_wt<<<448, 256, 0, stream>>>(W[4], Wt4, 300, 400, 40);
    convert_wt<<<64, 256, 0, stream>>>(W[5], Wt5, 400, 2, 52);
    pack_h<<<512, 256, 0, stream>>>(H, Hp);

    // ---- six uniform fused layers: X_{i+1} = relu(DAD @ (X_i W + b)), LIFO-alternating ----
    fused_layer<4,  false><<<BB * 7, 256, 0, stream>>>(Hp,   Wt0, Bv[0], dadpsm, bufA, 400, 416, 7, 0);
    fused_layer<52, false><<<BB * 5, 256, 0, stream>>>(bufA, Wt1, Bv[1], dadpsm, bufB, 300, 320, 5, 1);
    fused_layer<40, false><<<BB * 2, 256, 0, stream>>>(bufB, Wt2, Bv[2], dadpsm, bufA, 100, 128, 2, 0);
    fused_layer<16, false><<<BB * 5, 256, 0, stream>>>(bufA, Wt3, Bv[3], dadpsp, bufB, 300, 320, 5, 1);
    fused_layer<40, false><<<BB * 7, 256, 0, stream>>>(bufB, Wt4, Bv[4], dadpsp, bufA, 400, 416, 7, 0);
    fused_layer<52, true ><<<BB * 1, 256, 0, stream>>>(bufA, Wt5, Bv[5], dadpsp, d_out, 2, 2, 1, 1);
}